// Round 5
// baseline (2492.775 us; speedup 1.0000x reference)
//
#include <hip/hip_runtime.h>
#include <hip/hip_bf16.h>

#define BB 256
#define TT 512
#define DD 256
#define HH 512
#define G4H 2048
#define KTOT 768

typedef unsigned short u16;
typedef unsigned int u32;
typedef __attribute__((ext_vector_type(8))) short bf16x8;
typedef __attribute__((ext_vector_type(16))) float f32x16;

__device__ __forceinline__ u16 f2bf(float f) {
  union { float f; unsigned u; } v; v.f = f;
  unsigned r = v.u + 0x7FFFu + ((v.u >> 16) & 1u);
  return (u16)(r >> 16);
}
__device__ __forceinline__ float bf2f(u16 b) {
  union { unsigned u; float f; } v; v.u = ((unsigned)b) << 16;
  return v.f;
}
__device__ __forceinline__ float fsigmoid(float x) { return 1.f / (1.f + __expf(-x)); }
__device__ __forceinline__ float ftanh(float x) { return 1.f - 2.f / (__expf(2.f * x) + 1.f); }

__device__ __forceinline__ bf16x8 ld16_sc(const u16* p) {
  bf16x8 r;
  asm volatile("global_load_dwordx4 %0, %1, off sc0 sc1" : "=v"(r) : "v"(p) : "memory");
  return r;
}
__device__ __forceinline__ void st4_sc(u16* p, u32 v) {
  asm volatile("global_store_dword %0, %1, off sc0 sc1" :: "v"(p), "v"(v) : "memory");
}
__device__ __forceinline__ void waitv0() {
  asm volatile("s_waitcnt vmcnt(0)" ::: "memory");
}

// Wc rows permuted per hidden-slice: row = sl*64 + nb*32 + col', where
// (nb, col') -> gate q = nb*2 + (col'>>4), unit u = col'&15.
__global__ __launch_bounds__(256) void lstm_init(
    const float* __restrict__ W_ih, const float* __restrict__ W_hh,
    const float* __restrict__ b_ih, const float* __restrict__ b_hh,
    u16* __restrict__ Wc, float* __restrict__ bsum,
    u16* __restrict__ h0, u32* __restrict__ flags)
{
  int idx = blockIdx.x * 256 + threadIdx.x;
  if (idx < G4H * KTOT) {
    int r = idx / KTOT, k = idx - r * KTOT;
    int slp = r >> 6, rem = r & 63;
    int q = ((rem >> 5) << 1) | ((rem >> 4) & 1);
    int u = rem & 15;
    int srow = q * HH + slp * 16 + u;
    float v = (k < HH) ? W_hh[srow * HH + k] : W_ih[srow * DD + (k - HH)];
    Wc[idx] = f2bf(v);
  }
  if (idx < G4H) bsum[idx] = b_ih[idx] + b_hh[idx];
  if (idx < BB * HH) h0[idx] = (u16)0;
  if (idx < 256) flags[idx] = 0u;
}

// x [b][t][d] f32 -> xbf2 [t][b][d] bf16
__global__ __launch_bounds__(256) void xconv(const float* __restrict__ x, u16* __restrict__ xbf2)
{
  size_t g = (size_t)blockIdx.x * 256 + threadIdx.x;
  int d8 = (int)(g & 31);
  int b  = (int)((g >> 5) & 255);
  int t  = (int)(g >> 13);
  const float* src = x + ((size_t)b * TT + t) * DD + d8 * 8;
  float4 a = *(const float4*)(src);
  float4 c = *(const float4*)(src + 4);
  bf16x8 v;
  v[0] = (short)f2bf(a.x); v[1] = (short)f2bf(a.y);
  v[2] = (short)f2bf(a.z); v[3] = (short)f2bf(a.w);
  v[4] = (short)f2bf(c.x); v[5] = (short)f2bf(c.y);
  v[6] = (short)f2bf(c.z); v[7] = (short)f2bf(c.w);
  *(bf16x8*)(xbf2 + ((size_t)t * BB + b) * DD + d8 * 8) = v;
}

// Persistent recurrence. 256 WGs (1/CU), WG=(bg of 32 batches)x(sl of 16 units).
// Wave wv: n-block nb=wv&1, K-half kh=wv>>1. W frags resident in VGPRs.
// Alds: 48 kc-blocks of 1KB, slot = lane ^ ((kc&15)<<2) -> conflict-free.
// kc 0..31 = h (k 0..511), kc 32..47 = x (k 512..767).
__global__ __launch_bounds__(256, 1) void lstm_persist(
    const u16* __restrict__ xbf2, const u16* __restrict__ Wc,
    const float* __restrict__ bsum, u16* __restrict__ h_buf,
    u32* flags)
{
  __shared__ __align__(16) unsigned char Alds[49152];
  __shared__ float g4[2][2][32][66];

  const int tid  = threadIdx.x;
  const int bg   = blockIdx.x & 7;
  const int sl   = blockIdx.x >> 3;
  const int lane = tid & 63;
  const int wv   = tid >> 6;
  const int nb   = wv & 1;
  const int kh   = wv >> 1;
  const int l31  = lane & 31;
  const int lhi  = lane >> 5;

  // W fragments -> VGPRs (resident). B-frag: n=lane&31, k=kc*16+(lane>>5)*8+j
  bf16x8 wh[16], wx[8];
  {
    const u16* wb = Wc + (size_t)(sl * 64 + nb * 32 + l31) * KTOT + lhi * 8;
    #pragma unroll
    for (int i = 0; i < 16; ++i) wh[i] = *(const bf16x8*)(wb + kh * 256 + i * 16);
    #pragma unroll
    for (int i = 0; i < 8; ++i)  wx[i] = *(const bf16x8*)(wb + 512 + kh * 128 + i * 16);
  }

  const int pb2 = tid >> 3;
  const int pu2 = (tid & 7) * 2;
  const int hu2 = sl * 16 + pu2;
  const int gb2 = bg * 32 + pb2;
  const float bi0 = bsum[hu2],          bi1 = bsum[hu2 + 1];
  const float bf0 = bsum[HH + hu2],     bf1 = bsum[HH + hu2 + 1];
  const float bg0 = bsum[2 * HH + hu2], bg1 = bsum[2 * HH + hu2 + 1];
  const float bo0 = bsum[3 * HH + hu2], bo1 = bsum[3 * HH + hu2 + 1];
  float c0 = 0.f, c1 = 0.f;
  u32* myflags = flags + bg * 32;

  // x slab -> Alds kc 32..47 (wave-linear kc-block writes: conflict-free)
  auto stage_x = [&](int tt) {
    #pragma unroll
    for (int j = 0; j < 4; ++j) {
      int idx = j * 256 + tid;
      int row = idx & 31, d8 = idx >> 5;
      bf16x8 v = *(const bf16x8*)(xbf2 + ((size_t)tt * BB + bg * 32 + row) * DD + d8 * 8);
      int kc = 32 + (d8 >> 1);
      int slot = (((d8 & 1) << 5) | row) ^ ((kc & 15) << 2);
      *(bf16x8*)(Alds + kc * 1024 + slot * 16) = v;
    }
  };

  stage_x(0);   // prologue; drains at first B1

  for (int t = 0; t < TT; ++t) {
    const u16* __restrict__ h_in  = h_buf + (t & 1) * (BB * HH);
    u16* __restrict__ h_out = h_buf + ((t + 1) & 1) * (BB * HH);

    // wait for step t-1 producers: relaxed sc1 poll, throttled (s_sleep)
    if (t > 0 && wv == 0 && lane < 32) {
      while (__hip_atomic_load(&myflags[lane], __ATOMIC_RELAXED, __HIP_MEMORY_SCOPE_AGENT) < (u32)t)
        __builtin_amdgcn_s_sleep(1);
    }
    __syncthreads();   // B1

    // issue coherent h loads; x-part MFMA hides the LLC latency
    bf16x8 hv[8];
    #pragma unroll
    for (int j = 0; j < 8; ++j) {
      int idx = j * 256 + tid;
      int row = idx & 31, col8 = idx >> 5;
      hv[j] = ld16_sc(h_in + (size_t)(bg * 32 + row) * HH + col8 * 8);
    }
    f32x16 accA = {0,0,0,0,0,0,0,0,0,0,0,0,0,0,0,0};
    f32x16 accB = {0,0,0,0,0,0,0,0,0,0,0,0,0,0,0,0};
    #pragma unroll
    for (int i = 0; i < 8; ++i) {
      int kc = 32 + kh * 8 + i;
      bf16x8 a = *(const bf16x8*)(Alds + kc * 1024 + (size_t)((lane ^ ((kc & 15) << 2)) * 16));
      if (i & 1) accB = __builtin_amdgcn_mfma_f32_32x32x16_bf16(a, wx[i], accB, 0, 0, 0);
      else       accA = __builtin_amdgcn_mfma_f32_32x32x16_bf16(a, wx[i], accA, 0, 0, 0);
    }
    waitv0();                              // h in regs
    __builtin_amdgcn_sched_barrier(0);
    #pragma unroll
    for (int j = 0; j < 8; ++j) {
      int idx = j * 256 + tid;
      int row = idx & 31, col8 = idx >> 5;
      int kc = col8 >> 1;
      int slot = (((col8 & 1) << 5) | row) ^ ((kc & 15) << 2);
      *(bf16x8*)(Alds + kc * 1024 + slot * 16) = hv[j];
    }
    __syncthreads();   // B2

    // stage x(t+1) here: hidden under the h-part MFMA phase (x region dead until next x-MFMA)
    if (t + 1 < TT) stage_x(t + 1);

    // h-part MFMA (16 kc per wave)
    #pragma unroll
    for (int i = 0; i < 16; ++i) {
      int kc = kh * 16 + i;
      bf16x8 a = *(const bf16x8*)(Alds + kc * 1024 + (size_t)((lane ^ ((kc & 15) << 2)) * 16));
      if (i & 1) accB = __builtin_amdgcn_mfma_f32_32x32x16_bf16(a, wh[i], accB, 0, 0, 0);
      else       accA = __builtin_amdgcn_mfma_f32_32x32x16_bf16(a, wh[i], accA, 0, 0, 0);
    }
    // C/D layout (m74/m101): col = lane&31, row = (reg&3) + 8*(reg>>2) + 4*(lane>>5)
    #pragma unroll
    for (int r = 0; r < 16; ++r) {
      int grow = (r & 3) + 8 * (r >> 2) + 4 * lhi;
      g4[kh][nb][grow][l31] = accA[r] + accB[r];
    }
    __syncthreads();   // B3

    // pointwise: sum K-halves, cell update, packed coherent h store
    {
      float gi0 = g4[0][0][pb2][pu2]      + g4[1][0][pb2][pu2]      + bi0;
      float gf_0 = g4[0][0][pb2][16 + pu2] + g4[1][0][pb2][16 + pu2] + bf0;
      float gg0 = g4[0][1][pb2][pu2]      + g4[1][1][pb2][pu2]      + bg0;
      float go0 = g4[0][1][pb2][16 + pu2] + g4[1][1][pb2][16 + pu2] + bo0;
      float gi1 = g4[0][0][pb2][pu2 + 1]      + g4[1][0][pb2][pu2 + 1]      + bi1;
      float gf_1 = g4[0][0][pb2][17 + pu2] + g4[1][0][pb2][17 + pu2] + bf1;
      float gg1 = g4[0][1][pb2][pu2 + 1]      + g4[1][1][pb2][pu2 + 1]      + bg1;
      float go1 = g4[0][1][pb2][17 + pu2] + g4[1][1][pb2][17 + pu2] + bo1;
      c0 = fsigmoid(gf_0) * c0 + fsigmoid(gi0) * ftanh(gg0);
      c1 = fsigmoid(gf_1) * c1 + fsigmoid(gi1) * ftanh(gg1);
      u32 ha = (u32)f2bf(fsigmoid(go0) * ftanh(c0));
      u32 hb = (u32)f2bf(fsigmoid(go1) * ftanh(c1));
      st4_sc(h_out + (size_t)gb2 * HH + hu2, ha | (hb << 16));
    }
    waitv0();          // own h stores at coherent point
    __syncthreads();   // B4
    if (tid == 0)
      __hip_atomic_store(&myflags[sl], (u32)(t + 1), __ATOMIC_RELAXED, __HIP_MEMORY_SCOPE_AGENT);
  }
}

__global__ __launch_bounds__(256) void lstm_final(
    const u16* __restrict__ h, const float* __restrict__ fc_w,
    const float* __restrict__ fc_b, float* __restrict__ out)
{
  int b = threadIdx.x;
  float s = 0.f;
  const u16* hp = h + (size_t)b * HH;
  #pragma unroll 8
  for (int k = 0; k < HH; k += 8) {
    bf16x8 v = *(const bf16x8*)(hp + k);
    #pragma unroll
    for (int j = 0; j < 8; ++j) s += bf2f((u16)v[j]) * fc_w[k + j];
  }
  s += fc_b[0];
  out[b] = fsigmoid(s);
}

extern "C" void kernel_launch(void* const* d_in, const int* in_sizes, int n_in,
                              void* d_out, int out_size, void* d_ws, size_t ws_size,
                              hipStream_t stream) {
  (void)in_sizes; (void)n_in; (void)out_size; (void)ws_size;
  const float* x    = (const float*)d_in[0];
  const float* W_ih = (const float*)d_in[1];
  const float* W_hh = (const float*)d_in[2];
  const float* b_ih = (const float*)d_in[3];
  const float* b_hh = (const float*)d_in[4];
  const float* fc_w = (const float*)d_in[5];
  const float* fc_b = (const float*)d_in[6];
  float* out = (float*)d_out;

  char* ws = (char*)d_ws;
  u16*   Wc    = (u16*)(ws);                 // 3,145,728 B (permuted rows)
  float* bsum  = (float*)(ws + 3145728);     //     8,192 B
  u16*   h_buf = (u16*)(ws + 3153920);       //   524,288 B
  u32*   flags = (u32*)(ws + 3678208);       //     1,024 B
  u16*   xbf2  = (u16*)(ws + 4194304);       // 67,108,864 B

  lstm_init<<<6144, 256, 0, stream>>>(W_ih, W_hh, b_ih, b_hh, Wc, bsum, h_buf, flags);
  xconv<<<16384, 256, 0, stream>>>(x, xbf2);
  void* args[] = { (void*)&xbf2, (void*)&Wc, (void*)&bsum, (void*)&h_buf, (void*)&flags };
  (void)hipLaunchCooperativeKernel((void*)lstm_persist, dim3(256), dim3(256), args, 0, stream);
  lstm_final<<<1, 256, 0, stream>>>(h_buf, fc_w, fc_b, out);
}

// Round 7
// 2284.732 us; speedup vs baseline: 1.0911x; 1.0911x over previous
//
#include <hip/hip_runtime.h>
#include <hip/hip_bf16.h>

#define BB 256
#define TT 512
#define DD 256
#define HH 512
#define G4H 2048
#define KTOT 768
#define APITCH 1552   // 768*2 + 16B pad
#define WPITCH 1552

typedef unsigned short u16;
typedef unsigned int u32;
typedef __attribute__((ext_vector_type(8))) short bf16x8;
typedef __attribute__((ext_vector_type(4))) float f32x4;

__device__ __forceinline__ u16 f2bf(float f) {
  union { float f; unsigned u; } v; v.f = f;
  unsigned r = v.u + 0x7FFFu + ((v.u >> 16) & 1u);
  return (u16)(r >> 16);
}
__device__ __forceinline__ float bf2f(u16 b) {
  union { unsigned u; float f; } v; v.u = ((unsigned)b) << 16;
  return v.f;
}
__device__ __forceinline__ float fsigmoid(float x) { return 1.f / (1.f + __expf(-x)); }
__device__ __forceinline__ float ftanh(float x) { return 1.f - 2.f / (__expf(2.f * x) + 1.f); }

__device__ __forceinline__ bf16x8 ld16_sc(const u16* p) {
  bf16x8 r;
  asm volatile("global_load_dwordx4 %0, %1, off sc0 sc1" : "=v"(r) : "v"(p) : "memory");
  return r;
}
__device__ __forceinline__ void st4_sc(u16* p, u32 v) {
  asm volatile("global_store_dword %0, %1, off sc0 sc1" :: "v"(p), "v"(v) : "memory");
}
__device__ __forceinline__ void waitv0() {
  asm volatile("s_waitcnt vmcnt(0)" ::: "memory");
}

__global__ __launch_bounds__(256) void lstm_init(
    const float* __restrict__ W_ih, const float* __restrict__ W_hh,
    const float* __restrict__ b_ih, const float* __restrict__ b_hh,
    u16* __restrict__ Wc, float* __restrict__ bsum,
    u16* __restrict__ h0, u32* __restrict__ flags)
{
  int idx = blockIdx.x * 256 + threadIdx.x;
  if (idx < G4H * KTOT) {
    int r = idx / KTOT, k = idx - r * KTOT;
    float v = (k < HH) ? W_hh[r * HH + k] : W_ih[r * DD + (k - HH)];
    Wc[idx] = f2bf(v);
  }
  if (idx < G4H) bsum[idx] = b_ih[idx] + b_hh[idx];
  if (idx < BB * HH) h0[idx] = (u16)0;
  if (idx < 256) flags[idx] = 0u;
}

// x [b][t][d] f32 -> xbf2 [t][b][d] bf16 (per-step slab contiguous)
__global__ __launch_bounds__(256) void xconv(const float* __restrict__ x, u16* __restrict__ xbf2)
{
  size_t g = (size_t)blockIdx.x * 256 + threadIdx.x;
  int d8 = (int)(g & 31);
  int b  = (int)((g >> 5) & 255);
  int t  = (int)(g >> 13);
  const float* src = x + ((size_t)b * TT + t) * DD + d8 * 8;
  float4 a = *(const float4*)(src);
  float4 c = *(const float4*)(src + 4);
  bf16x8 v;
  v[0] = (short)f2bf(a.x); v[1] = (short)f2bf(a.y);
  v[2] = (short)f2bf(a.z); v[3] = (short)f2bf(a.w);
  v[4] = (short)f2bf(c.x); v[5] = (short)f2bf(c.y);
  v[6] = (short)f2bf(c.z); v[7] = (short)f2bf(c.w);
  *(bf16x8*)(xbf2 + ((size_t)t * BB + b) * DD + d8 * 8) = v;
}

// Persistent recurrence — r3 structure (16x16 MFMA, W resident in LDS, sc1 exchange).
// Single change vs r3: stage_x(t+1) moved into the store-drain shadow (after the
// h store, before waitv0/B4) so its L2 latency overlaps the mandatory drain.
__global__ __launch_bounds__(256, 1) void lstm_persist(
    const u16* __restrict__ xbf2, const u16* __restrict__ Wc,
    const float* __restrict__ bsum, u16* __restrict__ h_buf,
    u32* flags)
{
  __shared__ __align__(16) unsigned char Alds[32 * APITCH];   // 49,664 B
  __shared__ __align__(16) unsigned char Wlds[64 * WPITCH];   // 99,328 B (resident)
  __shared__ float g4[4][32][17];                             //  8,704 B

  const int tid  = threadIdx.x;
  const int bg   = blockIdx.x & 7;    // XCD-affine batch group
  const int sl   = blockIdx.x >> 3;   // hidden slice
  const int lane = tid & 63;
  const int wv   = tid >> 6;
  const int lrow = lane & 15;
  const int lkb  = lane >> 4;

  // one-time: W slice -> LDS
  #pragma unroll
  for (int j = 0; j < 24; ++j) {
    int c = tid + j * 256;
    int r = c / 96, col = c - r * 96;
    int q = r >> 4, u = r & 15;
    bf16x8 v = *(const bf16x8*)(Wc + (size_t)(q * HH + sl * 16 + u) * KTOT + col * 8);
    *(bf16x8*)(Wlds + r * WPITCH + col * 16) = v;
  }

  const int pb2 = tid >> 3;
  const int pu2 = (tid & 7) * 2;
  const int hu2 = sl * 16 + pu2;
  const int gb2 = bg * 32 + pb2;
  const float bi0 = bsum[hu2],          bi1 = bsum[hu2 + 1];
  const float bf0 = bsum[HH + hu2],     bf1 = bsum[HH + hu2 + 1];
  const float bg0 = bsum[2 * HH + hu2], bg1 = bsum[2 * HH + hu2 + 1];
  const float bo0 = bsum[3 * HH + hu2], bo1 = bsum[3 * HH + hu2 + 1];
  float c0 = 0.f, c1 = 0.f;
  u32* myflags = flags + bg * 32;

  // x slab (t-major) -> Alds x region
  auto stage_x = [&](int tt) {
    #pragma unroll
    for (int j = 0; j < 4; ++j) {
      int c = tid + j * 256;
      int row = c >> 5, col = c & 31;
      bf16x8 v = *(const bf16x8*)(xbf2 + ((size_t)tt * BB + bg * 32 + row) * DD + col * 8);
      *(bf16x8*)(Alds + row * APITCH + 1024 + col * 16) = v;
    }
  };

  stage_x(0);   // prologue; visible after first B1

  for (int t = 0; t < TT; ++t) {
    const u16* __restrict__ h_in  = h_buf + (t & 1) * (BB * HH);
    u16* __restrict__ h_out = h_buf + ((t + 1) & 1) * (BB * HH);

    // wait for step t-1 producers: relaxed sc1 poll, throttled
    if (t > 0 && wv == 0 && lane < 32) {
      while (__hip_atomic_load(&myflags[lane], __ATOMIC_RELAXED, __HIP_MEMORY_SCOPE_AGENT) < (u32)t)
        __builtin_amdgcn_s_sleep(1);
    }
    __syncthreads();   // B1

    // issue coherent h loads; x-part MFMA hides some of the LLC latency
    bf16x8 hv[8];
    #pragma unroll
    for (int j = 0; j < 8; ++j) {
      int idx = j * 256 + tid;
      int row = idx & 31, col8 = idx >> 5;
      hv[j] = ld16_sc(h_in + (size_t)(bg * 32 + row) * HH + col8 * 8);
    }
    f32x4 acc0 = {0.f, 0.f, 0.f, 0.f};
    f32x4 acc1 = {0.f, 0.f, 0.f, 0.f};
    {
      const unsigned aox = (unsigned)(lrow * APITCH + 1024 + lkb * 16);
      const unsigned wox = (unsigned)((wv * 16 + lrow) * WPITCH + 1024 + lkb * 16);
      #pragma unroll
      for (int kc = 0; kc < 8; ++kc) {
        bf16x8 bfr = *(const bf16x8*)(Wlds + wox + kc * 64);
        bf16x8 a0  = *(const bf16x8*)(Alds + aox + kc * 64);
        bf16x8 a1  = *(const bf16x8*)(Alds + aox + 16u * APITCH + kc * 64);
        acc0 = __builtin_amdgcn_mfma_f32_16x16x32_bf16(a0, bfr, acc0, 0, 0, 0);
        acc1 = __builtin_amdgcn_mfma_f32_16x16x32_bf16(a1, bfr, acc1, 0, 0, 0);
      }
    }
    waitv0();                              // h in regs
    __builtin_amdgcn_sched_barrier(0);
    #pragma unroll
    for (int j = 0; j < 8; ++j) {
      int idx = j * 256 + tid;
      int row = idx & 31, col8 = idx >> 5;
      *(bf16x8*)(Alds + row * APITCH + col8 * 16) = hv[j];
    }
    __syncthreads();   // B2

    // h-part MFMA (k 0..511)
    {
      const unsigned ao = (unsigned)(lrow * APITCH + lkb * 16);
      const unsigned wo = (unsigned)((wv * 16 + lrow) * WPITCH + lkb * 16);
      #pragma unroll
      for (int kc = 0; kc < 16; ++kc) {
        bf16x8 bfr = *(const bf16x8*)(Wlds + wo + kc * 64);
        bf16x8 a0  = *(const bf16x8*)(Alds + ao + kc * 64);
        bf16x8 a1  = *(const bf16x8*)(Alds + ao + 16u * APITCH + kc * 64);
        acc0 = __builtin_amdgcn_mfma_f32_16x16x32_bf16(a0, bfr, acc0, 0, 0, 0);
        acc1 = __builtin_amdgcn_mfma_f32_16x16x32_bf16(a1, bfr, acc1, 0, 0, 0);
      }
    }
    // C/D layout (m89): col = lane&15, row = (lane>>4)*4 + reg
    #pragma unroll
    for (int r = 0; r < 4; ++r) {
      g4[wv][lkb * 4 + r][lrow]      = acc0[r];
      g4[wv][16 + lkb * 4 + r][lrow] = acc1[r];
    }
    __syncthreads();   // B3

    // pointwise cell update; packed coherent h store
    {
      float gi0 = g4[0][pb2][pu2]     + bi0, gi1 = g4[0][pb2][pu2 + 1] + bi1;
      float gf_0 = g4[1][pb2][pu2]    + bf0, gf_1 = g4[1][pb2][pu2 + 1] + bf1;
      float gg0 = g4[2][pb2][pu2]     + bg0, gg1 = g4[2][pb2][pu2 + 1] + bg1;
      float go0 = g4[3][pb2][pu2]     + bo0, go1 = g4[3][pb2][pu2 + 1] + bo1;
      c0 = fsigmoid(gf_0) * c0 + fsigmoid(gi0) * ftanh(gg0);
      c1 = fsigmoid(gf_1) * c1 + fsigmoid(gi1) * ftanh(gg1);
      u32 ha = (u32)f2bf(fsigmoid(go0) * ftanh(c0));
      u32 hb = (u32)f2bf(fsigmoid(go1) * ftanh(c1));
      st4_sc(h_out + (size_t)gb2 * HH + hu2, ha | (hb << 16));
    }
    // stage x(t+1) in the drain shadow: its L2 latency overlaps the h-store drain.
    // LDS x region is dead here (last read drained at B2; next read after next B1).
    if (t + 1 < TT) stage_x(t + 1);
    waitv0();          // h store (and x loads) at coherent point
    __syncthreads();   // B4
    if (tid == 0)
      __hip_atomic_store(&myflags[sl], (u32)(t + 1), __ATOMIC_RELAXED, __HIP_MEMORY_SCOPE_AGENT);
  }
}

__global__ __launch_bounds__(256) void lstm_final(
    const u16* __restrict__ h, const float* __restrict__ fc_w,
    const float* __restrict__ fc_b, float* __restrict__ out)
{
  int b = threadIdx.x;
  float s = 0.f;
  const u16* hp = h + (size_t)b * HH;
  #pragma unroll 8
  for (int k = 0; k < HH; k += 8) {
    bf16x8 v = *(const bf16x8*)(hp + k);
    #pragma unroll
    for (int j = 0; j < 8; ++j) s += bf2f((u16)v[j]) * fc_w[k + j];
  }
  s += fc_b[0];
  out[b] = fsigmoid(s);
}

extern "C" void kernel_launch(void* const* d_in, const int* in_sizes, int n_in,
                              void* d_out, int out_size, void* d_ws, size_t ws_size,
                              hipStream_t stream) {
  (void)in_sizes; (void)n_in; (void)out_size; (void)ws_size;
  const float* x    = (const float*)d_in[0];
  const float* W_ih = (const float*)d_in[1];
  const float* W_hh = (const float*)d_in[2];
  const float* b_ih = (const float*)d_in[3];
  const float* b_hh = (const float*)d_in[4];
  const float* fc_w = (const float*)d_in[5];
  const float* fc_b = (const float*)d_in[6];
  float* out = (float*)d_out;

  char* ws = (char*)d_ws;
  u16*   Wc    = (u16*)(ws);                 // 3,145,728 B
  float* bsum  = (float*)(ws + 3145728);     //     8,192 B
  u16*   h_buf = (u16*)(ws + 3153920);       //   524,288 B
  u32*   flags = (u32*)(ws + 3678208);       //     1,024 B
  u16*   xbf2  = (u16*)(ws + 4194304);       // 67,108,864 B

  lstm_init<<<6144, 256, 0, stream>>>(W_ih, W_hh, b_ih, b_hh, Wc, bsum, h_buf, flags);
  xconv<<<16384, 256, 0, stream>>>(x, xbf2);
  void* args[] = { (void*)&xbf2, (void*)&Wc, (void*)&bsum, (void*)&h_buf, (void*)&flags };
  (void)hipLaunchCooperativeKernel((void*)lstm_persist, dim3(256), dim3(256), args, 0, stream);
  lstm_final<<<1, 256, 0, stream>>>(h_buf, fc_w, fc_b, out);
}

// Round 9
// 2129.630 us; speedup vs baseline: 1.1705x; 1.0728x over previous
//
#include <hip/hip_runtime.h>
#include <hip/hip_bf16.h>

#define BB 256
#define TT 512
#define DD 256
#define HH 512
#define G4H 2048
#define KTOT 768
#define APITCH 1552   // 768*2 + 16B pad
#define WPITCH 1552

typedef unsigned short u16;
typedef unsigned int u32;
typedef __attribute__((ext_vector_type(8))) short bf16x8;
typedef __attribute__((ext_vector_type(4))) float f32x4;

__device__ __forceinline__ u16 f2bf(float f) {
  union { float f; unsigned u; } v; v.f = f;
  unsigned r = v.u + 0x7FFFu + ((v.u >> 16) & 1u);
  return (u16)(r >> 16);
}
__device__ __forceinline__ float bf2f(u16 b) {
  union { unsigned u; float f; } v; v.u = ((unsigned)b) << 16;
  return v.f;
}
__device__ __forceinline__ float fsigmoid(float x) { return 1.f / (1.f + __expf(-x)); }
__device__ __forceinline__ float ftanh(float x) { return 1.f - 2.f / (__expf(2.f * x) + 1.f); }

// LLC-coherent (agent-safe) accesses: sc0 sc1. r8 lesson: SC bits are SCOPE
// (00=CU, 01=SE, 10=agent, 11=system); sc0-only is SE scope and DEADLOCKS a
// 32-CU group. There is no XCD-L2 scope — exchange must be LLC-level.
__device__ __forceinline__ bf16x8 ld16_sc(const u16* p) {
  bf16x8 r;
  asm volatile("global_load_dwordx4 %0, %1, off sc0 sc1" : "=v"(r) : "v"(p) : "memory");
  return r;
}
__device__ __forceinline__ void st4_sc(u16* p, u32 v) {
  asm volatile("global_store_dword %0, %1, off sc0 sc1" :: "v"(p), "v"(v) : "memory");
}
__device__ __forceinline__ void waitv0() {
  asm volatile("s_waitcnt vmcnt(0)" ::: "memory");
}

__global__ __launch_bounds__(256) void lstm_init(
    const float* __restrict__ W_ih, const float* __restrict__ W_hh,
    const float* __restrict__ b_ih, const float* __restrict__ b_hh,
    u16* __restrict__ Wc, float* __restrict__ bsum,
    u16* __restrict__ h0, u32* __restrict__ flags)
{
  int idx = blockIdx.x * 256 + threadIdx.x;
  if (idx < G4H * KTOT) {
    int r = idx / KTOT, k = idx - r * KTOT;
    float v = (k < HH) ? W_hh[r * HH + k] : W_ih[r * DD + (k - HH)];
    Wc[idx] = f2bf(v);
  }
  if (idx < G4H) bsum[idx] = b_ih[idx] + b_hh[idx];
  if (idx < BB * HH) h0[idx] = (u16)0;
  if (idx < 256) flags[idx] = 0u;
}

// x f32 -> bf16, same [b][t][d] layout (r3-exact)
__global__ __launch_bounds__(256) void xconv(const float* __restrict__ x, u16* __restrict__ xbf)
{
  size_t i = ((size_t)blockIdx.x * 256 + threadIdx.x) * 8;
  float4 a = *(const float4*)(x + i);
  float4 b = *(const float4*)(x + i + 4);
  bf16x8 v;
  v[0] = (short)f2bf(a.x); v[1] = (short)f2bf(a.y);
  v[2] = (short)f2bf(a.z); v[3] = (short)f2bf(a.w);
  v[4] = (short)f2bf(b.x); v[5] = (short)f2bf(b.y);
  v[6] = (short)f2bf(b.z); v[7] = (short)f2bf(b.w);
  *(bf16x8*)(xbf + i) = v;
}

// Persistent recurrence — r3 structure exactly, ONE change: after issuing the
// h loads, prefetch this wave's 24 W fragments LDS->regs (covers the h LLC RT
// with ~300cy of useful ds_reads, and removes the W reads from the post-load
// h-MFMA critical segment: 48 -> 32 LDS reads/wave there).
__global__ __launch_bounds__(256, 1) void lstm_persist(
    const u16* __restrict__ xbf, const u16* __restrict__ Wc,
    const float* __restrict__ bsum, u16* __restrict__ h_buf,
    u32* flags)
{
  __shared__ __align__(16) unsigned char Alds[32 * APITCH];   // 49,664 B
  __shared__ __align__(16) unsigned char Wlds[64 * WPITCH];   // 99,328 B (resident)
  __shared__ float g4[4][32][17];                             //  8,704 B

  const int tid  = threadIdx.x;
  const int bg   = blockIdx.x & 7;    // XCD-affine batch group
  const int sl   = blockIdx.x >> 3;   // hidden slice
  const int lane = tid & 63;
  const int wv   = tid >> 6;
  const int lrow = lane & 15;
  const int lkb  = lane >> 4;

  // one-time: W slice -> LDS
  #pragma unroll
  for (int j = 0; j < 24; ++j) {
    int c = tid + j * 256;
    int r = c / 96, col = c - r * 96;
    int q = r >> 4, u = r & 15;
    bf16x8 v = *(const bf16x8*)(Wc + (size_t)(q * HH + sl * 16 + u) * KTOT + col * 8);
    *(bf16x8*)(Wlds + r * WPITCH + col * 16) = v;
  }

  const int pb2 = tid >> 3;
  const int pu2 = (tid & 7) * 2;
  const int hu2 = sl * 16 + pu2;
  const int gb2 = bg * 32 + pb2;
  const float bi0 = bsum[hu2],          bi1 = bsum[hu2 + 1];
  const float bf0 = bsum[HH + hu2],     bf1 = bsum[HH + hu2 + 1];
  const float bg0 = bsum[2 * HH + hu2], bg1 = bsum[2 * HH + hu2 + 1];
  const float bo0 = bsum[3 * HH + hu2], bo1 = bsum[3 * HH + hu2 + 1];
  float c0 = 0.f, c1 = 0.f;
  u32* myflags = flags + bg * 32;

  for (int t = 0; t < TT; ++t) {
    const u16* __restrict__ h_in  = h_buf + (t & 1) * (BB * HH);
    u16* __restrict__ h_out = h_buf + ((t + 1) & 1) * (BB * HH);

    // stage x tile (plain cached loads; overlaps the wait — free window)
    #pragma unroll
    for (int j = 0; j < 4; ++j) {
      int c = tid + j * 256;
      int row = c >> 5, col = c & 31;
      bf16x8 v = *(const bf16x8*)(xbf + ((size_t)(bg * 32 + row) * TT + t) * DD + col * 8);
      *(bf16x8*)(Alds + row * APITCH + 1024 + col * 16) = v;
    }
    // wait for step t-1 producers: relaxed sc1 poll, throttled
    if (t > 0 && wv == 0 && lane < 32) {
      while (__hip_atomic_load(&myflags[lane], __ATOMIC_RELAXED, __HIP_MEMORY_SCOPE_AGENT) < (u32)t)
        __builtin_amdgcn_s_sleep(1);
    }
    __syncthreads();   // B1  -- B1->flag-store below is the global period; keep it minimal

    // issue coherent h loads (starts the LLC RT clock)
    bf16x8 hv[8];
    #pragma unroll
    for (int j = 0; j < 8; ++j) {
      int idx = j * 256 + tid;
      int row = idx & 31, col8 = idx >> 5;
      hv[j] = ld16_sc(h_in + (size_t)(bg * 32 + row) * HH + col8 * 8);
    }
    // W prefetch: all 24 kc fragments for this wave -> regs (covering work)
    bf16x8 wfr[24];
    {
      const unsigned wbase = (unsigned)((wv * 16 + lrow) * WPITCH + lkb * 16);
      #pragma unroll
      for (int kc = 0; kc < 16; ++kc) wfr[kc] = *(const bf16x8*)(Wlds + wbase + kc * 64);
      #pragma unroll
      for (int kc = 0; kc < 8; ++kc)  wfr[16 + kc] = *(const bf16x8*)(Wlds + wbase + 1024 + kc * 64);
    }
    __builtin_amdgcn_sched_barrier(0);   // pin the prefetch into the h-flight window
    // x-part MFMA (k 512..767) — A from LDS, W from regs
    f32x4 acc0 = {0.f, 0.f, 0.f, 0.f};
    f32x4 acc1 = {0.f, 0.f, 0.f, 0.f};
    {
      const unsigned aox = (unsigned)(lrow * APITCH + 1024 + lkb * 16);
      #pragma unroll
      for (int kc = 0; kc < 8; ++kc) {
        bf16x8 a0 = *(const bf16x8*)(Alds + aox + kc * 64);
        bf16x8 a1 = *(const bf16x8*)(Alds + aox + 16u * APITCH + kc * 64);
        acc0 = __builtin_amdgcn_mfma_f32_16x16x32_bf16(a0, wfr[16 + kc], acc0, 0, 0, 0);
        acc1 = __builtin_amdgcn_mfma_f32_16x16x32_bf16(a1, wfr[16 + kc], acc1, 0, 0, 0);
      }
    }
    waitv0();                              // h in regs
    __builtin_amdgcn_sched_barrier(0);
    #pragma unroll
    for (int j = 0; j < 8; ++j) {
      int idx = j * 256 + tid;
      int row = idx & 31, col8 = idx >> 5;
      *(bf16x8*)(Alds + row * APITCH + col8 * 16) = hv[j];
    }
    __syncthreads();   // B2

    // h-part MFMA (k 0..511) — A from LDS, W from regs (32 ds_reads/wave)
    {
      const unsigned ao = (unsigned)(lrow * APITCH + lkb * 16);
      #pragma unroll
      for (int kc = 0; kc < 16; ++kc) {
        bf16x8 a0 = *(const bf16x8*)(Alds + ao + kc * 64);
        bf16x8 a1 = *(const bf16x8*)(Alds + ao + 16u * APITCH + kc * 64);
        acc0 = __builtin_amdgcn_mfma_f32_16x16x32_bf16(a0, wfr[kc], acc0, 0, 0, 0);
        acc1 = __builtin_amdgcn_mfma_f32_16x16x32_bf16(a1, wfr[kc], acc1, 0, 0, 0);
      }
    }
    // C/D layout (m89): col = lane&15, row = (lane>>4)*4 + reg
    #pragma unroll
    for (int r = 0; r < 4; ++r) {
      g4[wv][lkb * 4 + r][lrow]      = acc0[r];
      g4[wv][16 + lkb * 4 + r][lrow] = acc1[r];
    }
    __syncthreads();   // B3

    // pointwise cell update; packed coherent h store
    {
      float gi0 = g4[0][pb2][pu2]     + bi0, gi1 = g4[0][pb2][pu2 + 1] + bi1;
      float gf_0 = g4[1][pb2][pu2]    + bf0, gf_1 = g4[1][pb2][pu2 + 1] + bf1;
      float gg0 = g4[2][pb2][pu2]     + bg0, gg1 = g4[2][pb2][pu2 + 1] + bg1;
      float go0 = g4[3][pb2][pu2]     + bo0, go1 = g4[3][pb2][pu2 + 1] + bo1;
      c0 = fsigmoid(gf_0) * c0 + fsigmoid(gi0) * ftanh(gg0);
      c1 = fsigmoid(gf_1) * c1 + fsigmoid(gi1) * ftanh(gg1);
      u32 ha = (u32)f2bf(fsigmoid(go0) * ftanh(c0));
      u32 hb = (u32)f2bf(fsigmoid(go1) * ftanh(c1));
      st4_sc(h_out + (size_t)gb2 * HH + hu2, ha | (hb << 16));
    }
    waitv0();          // h stores at the LLC (coherent point)
    __syncthreads();   // B4
    if (tid == 0)
      __hip_atomic_store(&myflags[sl], (u32)(t + 1), __ATOMIC_RELAXED, __HIP_MEMORY_SCOPE_AGENT);
  }
}

__global__ __launch_bounds__(256) void lstm_final(
    const u16* __restrict__ h, const float* __restrict__ fc_w,
    const float* __restrict__ fc_b, float* __restrict__ out)
{
  int b = threadIdx.x;
  float s = 0.f;
  const u16* hp = h + (size_t)b * HH;
  #pragma unroll 8
  for (int k = 0; k < HH; k += 8) {
    bf16x8 v = *(const bf16x8*)(hp + k);
    #pragma unroll
    for (int j = 0; j < 8; ++j) s += bf2f((u16)v[j]) * fc_w[k + j];
  }
  s += fc_b[0];
  out[b] = fsigmoid(s);
}

extern "C" void kernel_launch(void* const* d_in, const int* in_sizes, int n_in,
                              void* d_out, int out_size, void* d_ws, size_t ws_size,
                              hipStream_t stream) {
  (void)in_sizes; (void)n_in; (void)out_size; (void)ws_size;
  const float* x    = (const float*)d_in[0];
  const float* W_ih = (const float*)d_in[1];
  const float* W_hh = (const float*)d_in[2];
  const float* b_ih = (const float*)d_in[3];
  const float* b_hh = (const float*)d_in[4];
  const float* fc_w = (const float*)d_in[5];
  const float* fc_b = (const float*)d_in[6];
  float* out = (float*)d_out;

  char* ws = (char*)d_ws;
  u16*   Wc    = (u16*)(ws);                 // 3,145,728 B
  float* bsum  = (float*)(ws + 3145728);     //     8,192 B
  u16*   h_buf = (u16*)(ws + 3153920);       //   524,288 B
  u32*   flags = (u32*)(ws + 3678208);       //     1,024 B
  u16*   xbf   = (u16*)(ws + 4194304);       // 67,108,864 B

  lstm_init<<<6144, 256, 0, stream>>>(W_ih, W_hh, b_ih, b_hh, Wc, bsum, h_buf, flags);
  xconv<<<16384, 256, 0, stream>>>(x, xbf);
  void* args[] = { (void*)&xbf, (void*)&Wc, (void*)&bsum, (void*)&h_buf, (void*)&flags };
  (void)hipLaunchCooperativeKernel((void*)lstm_persist, dim3(256), dim3(256), args, 0, stream);
  lstm_final<<<1, 256, 0, stream>>>(h_buf, fc_w, fc_b, out);
}

// Round 10
// 2103.556 us; speedup vs baseline: 1.1850x; 1.0124x over previous
//
#include <hip/hip_runtime.h>
#include <hip/hip_bf16.h>

#define BB 256
#define TT 512
#define DD 256
#define HH 512
#define G4H 2048
#define KTOT 768

typedef unsigned short u16;
typedef unsigned int u32;
typedef __attribute__((ext_vector_type(8))) short bf16x8;
typedef __attribute__((ext_vector_type(4))) float f32x4;

__device__ __forceinline__ u16 f2bf(float f) {
  union { float f; unsigned u; } v; v.f = f;
  unsigned r = v.u + 0x7FFFu + ((v.u >> 16) & 1u);
  return (u16)(r >> 16);
}
__device__ __forceinline__ float bf2f(u16 b) {
  union { unsigned u; float f; } v; v.u = ((unsigned)b) << 16;
  return v.f;
}
__device__ __forceinline__ float fsigmoid(float x) { return 1.f / (1.f + __expf(-x)); }
__device__ __forceinline__ float ftanh(float x) { return 1.f - 2.f / (__expf(2.f * x) + 1.f); }

// LLC-coherent (agent-safe) accesses. r8 lesson: sc0-only is SE scope -> deadlock;
// exchange must be LLC-level (sc0 sc1).
__device__ __forceinline__ bf16x8 ld16_sc(const u16* p) {
  bf16x8 r;
  asm volatile("global_load_dwordx4 %0, %1, off sc0 sc1" : "=v"(r) : "v"(p) : "memory");
  return r;
}
__device__ __forceinline__ void st4_sc(u16* p, u32 v) {
  asm volatile("global_store_dword %0, %1, off sc0 sc1" :: "v"(p), "v"(v) : "memory");
}
__device__ __forceinline__ void waitv0() {
  asm volatile("s_waitcnt vmcnt(0)" ::: "memory");
}

__global__ __launch_bounds__(256) void lstm_init(
    const float* __restrict__ W_ih, const float* __restrict__ W_hh,
    const float* __restrict__ b_ih, const float* __restrict__ b_hh,
    u16* __restrict__ Wc, float* __restrict__ bsum,
    u16* __restrict__ h0, u32* __restrict__ flags)
{
  int idx = blockIdx.x * 256 + threadIdx.x;
  if (idx < G4H * KTOT) {
    int r = idx / KTOT, k = idx - r * KTOT;
    float v = (k < HH) ? W_hh[r * HH + k] : W_ih[r * DD + (k - HH)];
    Wc[idx] = f2bf(v);
  }
  if (idx < G4H) bsum[idx] = b_ih[idx] + b_hh[idx];
  if (idx < BB * HH) h0[idx] = (u16)0;
  if (idx < 256) flags[idx] = 0u;
}

// x [b][t][d] f32 -> xs: per-(t,bg) 16KB slab in the EXACT LDS fragment image:
// byte = blk*2048 + half*1024 + slot'*16, slot' = (lkb*16+lrow) ^ blk
// (blk = x kc-block 0..7, global kc = 16+blk, swz = (16+blk)&7 = blk).
__global__ __launch_bounds__(256) void xconv(const float* __restrict__ x, u16* __restrict__ xs)
{
  size_t g = (size_t)blockIdx.x * 256 + threadIdx.x;   // 4,194,304 chunks of 16B
  int slot_p = (int)(g & 63);
  int half   = (int)((g >> 6) & 1);
  int blk    = (int)((g >> 7) & 7);
  int bg     = (int)((g >> 10) & 7);
  int t      = (int)(g >> 13);
  int slot = slot_p ^ blk;
  int lkb = slot >> 4, lrow = slot & 15;
  int b = bg * 32 + half * 16 + lrow;
  int d0 = blk * 32 + lkb * 8;
  const float* src = x + ((size_t)b * TT + t) * DD + d0;
  float4 a = *(const float4*)(src);
  float4 c = *(const float4*)(src + 4);
  bf16x8 v;
  v[0] = (short)f2bf(a.x); v[1] = (short)f2bf(a.y);
  v[2] = (short)f2bf(a.z); v[3] = (short)f2bf(a.w);
  v[4] = (short)f2bf(c.x); v[5] = (short)f2bf(c.y);
  v[6] = (short)f2bf(c.z); v[7] = (short)f2bf(c.w);
  size_t dst_byte = ((size_t)t * 8 + bg) * 16384 + (size_t)(blk * 2048 + half * 1024 + slot_p * 16);
  *(bf16x8*)(xs + dst_byte / 2) = v;
}

// Persistent recurrence — r3 protocol/structure EXACTLY; only LDS layouts changed:
//  Alds: 24 kc-blocks x 2KB (kc 0..15 = h, 16..23 = x). Block = [half][slot'] where
//        slot' = (lkb*16+lrow) ^ (kc&7). Wave reads = permutation of contiguous 1KB
//        per block -> conflict-free; h-writes bank-balanced via the XOR.
//  Wlds: per (wave,kc) 1KB fragment blocks, slot = lkb*16+lrow (never written in-loop).
//  x staged as a linear 16KB memcpy (xconv pre-computed the fragment image).
__global__ __launch_bounds__(256, 1) void lstm_persist(
    const u16* __restrict__ xs, const u16* __restrict__ Wc,
    const float* __restrict__ bsum, u16* __restrict__ h_buf,
    u32* flags)
{
  __shared__ __align__(16) unsigned char Alds[49152];   // 24 x 2KB
  __shared__ __align__(16) unsigned char Wlds[98304];   // 4 waves x 24 kc x 1KB
  __shared__ float g4[4][32][17];                       // 8,704 B -> 156,160 total

  const int tid  = threadIdx.x;
  const int bg   = blockIdx.x & 7;    // XCD-affine batch group
  const int sl   = blockIdx.x >> 3;   // hidden slice
  const int lane = tid & 63;
  const int wv   = tid >> 6;
  const int lrow = lane & 15;
  const int lkb  = lane >> 4;

  // one-time: W slice -> LDS fragment blocks (global reads identical to r3)
  #pragma unroll
  for (int j = 0; j < 24; ++j) {
    int c = tid + j * 256;
    int r = c / 96, col = c - r * 96;     // r: gate row (q*16+u), col: 16B chunk (k)
    int q = r >> 4, u = r & 15;
    int kcg = col >> 2, wlkb = col & 3;
    bf16x8 v = *(const bf16x8*)(Wc + (size_t)(q * HH + sl * 16 + u) * KTOT + col * 8);
    *(bf16x8*)(Wlds + (size_t)((q * 24 + kcg) * 1024 + (wlkb * 16 + u) * 16)) = v;
  }

  const int pb2 = tid >> 3;
  const int pu2 = (tid & 7) * 2;
  const int hu2 = sl * 16 + pu2;
  const int gb2 = bg * 32 + pb2;
  const float bi0 = bsum[hu2],          bi1 = bsum[hu2 + 1];
  const float bf0 = bsum[HH + hu2],     bf1 = bsum[HH + hu2 + 1];
  const float bg0 = bsum[2 * HH + hu2], bg1 = bsum[2 * HH + hu2 + 1];
  const float bo0 = bsum[3 * HH + hu2], bo1 = bsum[3 * HH + hu2 + 1];
  float c0 = 0.f, c1 = 0.f;
  u32* myflags = flags + bg * 32;

  const unsigned slot0 = (unsigned)(lkb * 16 + lrow);   // this lane's fragment slot

  // x slab -> Alds x region: pure linear 16KB memcpy (coalesced + bank-balanced)
  auto stage_x = [&](int tt) {
    const u16* src = xs + (((size_t)tt * 8 + bg) * 16384) / 2;
    #pragma unroll
    for (int j = 0; j < 4; ++j) {
      int off = j * 4096 + tid * 16;
      bf16x8 v = *(const bf16x8*)(src + off / 2);
      *(bf16x8*)(Alds + 32768 + off) = v;
    }
  };

  for (int t = 0; t < TT; ++t) {
    const u16* __restrict__ h_in  = h_buf + (t & 1) * (BB * HH);
    u16* __restrict__ h_out = h_buf + ((t + 1) & 1) * (BB * HH);

    stage_x(t);   // overlaps the wait (free window)

    // wait for step t-1 producers: relaxed sc1 poll, throttled
    if (t > 0 && wv == 0 && lane < 32) {
      while (__hip_atomic_load(&myflags[lane], __ATOMIC_RELAXED, __HIP_MEMORY_SCOPE_AGENT) < (u32)t)
        __builtin_amdgcn_s_sleep(1);
    }
    __syncthreads();   // B1

    // issue coherent h loads (r3-identical mapping); x-part MFMA hides part of the RT
    bf16x8 hv[8];
    #pragma unroll
    for (int j = 0; j < 8; ++j) {
      int idx = j * 256 + tid;
      int row = idx & 31, col8 = idx >> 5;
      hv[j] = ld16_sc(h_in + (size_t)(bg * 32 + row) * HH + col8 * 8);
    }
    f32x4 acc0 = {0.f, 0.f, 0.f, 0.f};
    f32x4 acc1 = {0.f, 0.f, 0.f, 0.f};
    {
      #pragma unroll
      for (int kc = 0; kc < 8; ++kc) {
        int kcg = 16 + kc;   // swz = kcg&7 = kc
        bf16x8 bfr = *(const bf16x8*)(Wlds + (unsigned)((wv * 24 + kcg) * 1024) + slot0 * 16);
        unsigned ab = (unsigned)(kcg * 2048) + ((slot0 ^ (unsigned)kc) * 16);
        bf16x8 a0 = *(const bf16x8*)(Alds + ab);
        bf16x8 a1 = *(const bf16x8*)(Alds + ab + 1024);
        acc0 = __builtin_amdgcn_mfma_f32_16x16x32_bf16(a0, bfr, acc0, 0, 0, 0);
        acc1 = __builtin_amdgcn_mfma_f32_16x16x32_bf16(a1, bfr, acc1, 0, 0, 0);
      }
    }
    waitv0();                              // h in regs
    __builtin_amdgcn_sched_barrier(0);
    #pragma unroll
    for (int j = 0; j < 8; ++j) {
      int idx = j * 256 + tid;
      int row = idx & 31, col8 = idx >> 5;
      int kc = col8 >> 2, wlkb = col8 & 3, half = row >> 4, r15 = row & 15;
      unsigned slot_p = (unsigned)(wlkb * 16 + r15) ^ (unsigned)(kc & 7);
      *(bf16x8*)(Alds + (unsigned)(kc * 2048 + half * 1024) + slot_p * 16) = hv[j];
    }
    __syncthreads();   // B2

    // h-part MFMA (k 0..511)
    {
      #pragma unroll
      for (int kc = 0; kc < 16; ++kc) {
        bf16x8 bfr = *(const bf16x8*)(Wlds + (unsigned)((wv * 24 + kc) * 1024) + slot0 * 16);
        unsigned ab = (unsigned)(kc * 2048) + ((slot0 ^ (unsigned)(kc & 7)) * 16);
        bf16x8 a0 = *(const bf16x8*)(Alds + ab);
        bf16x8 a1 = *(const bf16x8*)(Alds + ab + 1024);
        acc0 = __builtin_amdgcn_mfma_f32_16x16x32_bf16(a0, bfr, acc0, 0, 0, 0);
        acc1 = __builtin_amdgcn_mfma_f32_16x16x32_bf16(a1, bfr, acc1, 0, 0, 0);
      }
    }
    // C/D layout (m89): col = lane&15, row = (lane>>4)*4 + reg
    #pragma unroll
    for (int r = 0; r < 4; ++r) {
      g4[wv][lkb * 4 + r][lrow]      = acc0[r];
      g4[wv][16 + lkb * 4 + r][lrow] = acc1[r];
    }
    __syncthreads();   // B3

    // pointwise cell update; packed coherent h store
    {
      float gi0 = g4[0][pb2][pu2]     + bi0, gi1 = g4[0][pb2][pu2 + 1] + bi1;
      float gf_0 = g4[1][pb2][pu2]    + bf0, gf_1 = g4[1][pb2][pu2 + 1] + bf1;
      float gg0 = g4[2][pb2][pu2]     + bg0, gg1 = g4[2][pb2][pu2 + 1] + bg1;
      float go0 = g4[3][pb2][pu2]     + bo0, go1 = g4[3][pb2][pu2 + 1] + bo1;
      c0 = fsigmoid(gf_0) * c0 + fsigmoid(gi0) * ftanh(gg0);
      c1 = fsigmoid(gf_1) * c1 + fsigmoid(gi1) * ftanh(gg1);
      u32 ha = (u32)f2bf(fsigmoid(go0) * ftanh(c0));
      u32 hb = (u32)f2bf(fsigmoid(go1) * ftanh(c1));
      st4_sc(h_out + (size_t)gb2 * HH + hu2, ha | (hb << 16));
    }
    waitv0();          // h stores at the LLC (coherent point)
    __syncthreads();   // B4
    if (tid == 0)
      __hip_atomic_store(&myflags[sl], (u32)(t + 1), __ATOMIC_RELAXED, __HIP_MEMORY_SCOPE_AGENT);
  }
}

__global__ __launch_bounds__(256) void lstm_final(
    const u16* __restrict__ h, const float* __restrict__ fc_w,
    const float* __restrict__ fc_b, float* __restrict__ out)
{
  int b = threadIdx.x;
  float s = 0.f;
  const u16* hp = h + (size_t)b * HH;
  #pragma unroll 8
  for (int k = 0; k < HH; k += 8) {
    bf16x8 v = *(const bf16x8*)(hp + k);
    #pragma unroll
    for (int j = 0; j < 8; ++j) s += bf2f((u16)v[j]) * fc_w[k + j];
  }
  s += fc_b[0];
  out[b] = fsigmoid(s);
}

extern "C" void kernel_launch(void* const* d_in, const int* in_sizes, int n_in,
                              void* d_out, int out_size, void* d_ws, size_t ws_size,
                              hipStream_t stream) {
  (void)in_sizes; (void)n_in; (void)out_size; (void)ws_size;
  const float* x    = (const float*)d_in[0];
  const float* W_ih = (const float*)d_in[1];
  const float* W_hh = (const float*)d_in[2];
  const float* b_ih = (const float*)d_in[3];
  const float* b_hh = (const float*)d_in[4];
  const float* fc_w = (const float*)d_in[5];
  const float* fc_b = (const float*)d_in[6];
  float* out = (float*)d_out;

  char* ws = (char*)d_ws;
  u16*   Wc    = (u16*)(ws);                 // 3,145,728 B
  float* bsum  = (float*)(ws + 3145728);     //     8,192 B
  u16*   h_buf = (u16*)(ws + 3153920);       //   524,288 B
  u32*   flags = (u32*)(ws + 3678208);       //     1,024 B
  u16*   xs    = (u16*)(ws + 4194304);       // 67,108,864 B (x, fragment-image slabs)

  lstm_init<<<6144, 256, 0, stream>>>(W_ih, W_hh, b_ih, b_hh, Wc, bsum, h_buf, flags);
  xconv<<<16384, 256, 0, stream>>>(x, xs);
  void* args[] = { (void*)&xs, (void*)&Wc, (void*)&bsum, (void*)&h_buf, (void*)&flags };
  (void)hipLaunchCooperativeKernel((void*)lstm_persist, dim3(256), dim3(256), args, 0, stream);
  lstm_final<<<1, 256, 0, stream>>>(h_buf, fc_w, fc_b, out);
}